// Round 8
// baseline (2037.456 us; speedup 1.0000x reference)
//
#include <hip/hip_runtime.h>
#include <cstdint>
#include <cstddef>

// GRU B=16384 T=64 H=32, 3 bidir layers + FC(64->2) + tanh.
// R7: R6 structure (permuted gate rows, D-frag==B-frag, zero LDS, exp2-folded
// weights, shared rcp, cvt_pk, 2x unroll, rec=(whhHi+whhLo)*hHi) with 8 seqs
// per wave instead of 16: 4096 waves = 4 waves/SIMD. MFMA cols 8-15 compute
// garbage that stays column-local (D[m][n] reads only B col n); their stores
// are masked. Doubles independent serial chains per SIMD to hide gate latency.

#define BB 16384
#define TT 64

typedef __attribute__((ext_vector_type(8))) short bf16x8;
typedef __attribute__((ext_vector_type(4))) float f32x4;

#if __has_builtin(__builtin_amdgcn_exp2f)
#define EXP2(x) __builtin_amdgcn_exp2f(x)
#else
#define EXP2(x) exp2f(x)
#endif
#if __has_builtin(__builtin_amdgcn_rcpf)
#define RCP(x) __builtin_amdgcn_rcpf(x)
#else
#define RCP(x) (1.0f / (x))
#endif

#define SR (-1.4426950408889634f)   // -log2(e)   for r,z gates
#define SN (-2.8853900817779268f)   // -2*log2(e) for n gate

__device__ __forceinline__ float tanh_fast(float x) { return 2.0f / (1.0f + __expf(-2.0f * x)) - 1.0f; }
__device__ __forceinline__ unsigned short f2bf(float f) {
    unsigned int u = __float_as_uint(f);
    u = u + 0x7fffu + ((u >> 16) & 1u);
    return (unsigned short)(u >> 16);
}
__device__ __forceinline__ float bf2f(unsigned short b) {
    return __uint_as_float(((unsigned int)b) << 16);
}
__device__ __forceinline__ unsigned int cvt_pk(float a, float b) {
#if __has_builtin(__builtin_amdgcn_cvt_pk_bf16_f32)
    typedef __bf16 bf16x2_t __attribute__((ext_vector_type(2)));
    bf16x2_t p = __builtin_amdgcn_cvt_pk_bf16_f32(a, b);
    return __builtin_bit_cast(unsigned int, p);
#else
    unsigned int ua = __float_as_uint(a), ub = __float_as_uint(b);
    unsigned int ha = (ua + 0x7fffu + ((ua >> 16) & 1u)) >> 16;
    unsigned int hb = (ub + 0x7fffu + ((ub >> 16) & 1u)) & 0xffff0000u;
    return ha | hb;
#endif
}
__device__ __forceinline__ f32x4 mfma16(bf16x8 a, bf16x8 b, f32x4 c) {
    return __builtin_amdgcn_mfma_f32_16x16x32_bf16(a, b, c, 0, 0, 0);
}

// Gates for a q-pair. Inputs are exp2-prescaled preactivations (C carried bias).
// sigma(x) = rcp(1+exp2(SR*x)); tanh(v) = 2*rcp(1+exp2(SN*v)) - 1.
__device__ __forceinline__ void gate_pair(float aR0, float aR1, float aZ0, float aZ1,
                                          float xN0, float xN1, float hN0, float hN1,
                                          float& hp0, float& hp1) {
    float er0 = EXP2(aR0), er1 = EXP2(aR1);
    float ez0 = EXP2(aZ0), ez1 = EXP2(aZ1);
    float Ar0 = 1.f + er0, Ar1 = 1.f + er1;
    float Az0 = 1.f + ez0, Az1 = 1.f + ez1;
    float iR = RCP(Ar0 * Ar1);
    float iZ = RCP(Az0 * Az1);
    float r0 = iR * Ar1, r1 = iR * Ar0;
    float z0 = iZ * Az1, z1 = iZ * Az0;
    float v0 = fmaf(r0, hN0, xN0), v1 = fmaf(r1, hN1, xN1);
    float en0 = EXP2(v0), en1 = EXP2(v1);
    float An0 = 1.f + en0, An1 = 1.f + en1;
    float iN = RCP(An0 * An1);
    float n0 = fmaf(2.f, iN * An1, -1.f);
    float n1 = fmaf(2.f, iN * An0, -1.f);
    hp0 = fmaf(z0, hp0 - n0, n0);
    hp1 = fmaf(z1, hp1 - n1, n1);
}

// A: lane = A[m=lane&15][k=(lane>>4)*8+j]   B: lane = B[k=(lane>>4)*8+j][n=lane&15]
// D: lane = D[row=(lane>>4)*4+reg][col=lane&15]
// Gate-row permutation: block row position (T*16 + qd*4 + q) <- original unit 8qd+4T+q.

template<bool IS_L0>
__global__ __launch_bounds__(256, 4)
void gru_mfma(const float* __restrict__ x0,
              const unsigned short* __restrict__ bin,
              const float* __restrict__ Wih,               // (2,96,I)
              const float* __restrict__ Whh,               // (2,96,32)
              const float* __restrict__ bih,               // (2,96)
              const float* __restrict__ bhh,               // (2,96)
              unsigned short* __restrict__ bout)           // (B,T,64) bf16
{
    const int tid  = threadIdx.x;
    const int lane = tid & 63;
    const int wv   = tid >> 6;
    const int g    = blockIdx.x * 4 + wv;        // 0..4095
    const int d    = g >> 11;
    const int b0   = (g & 2047) * 8;             // 8 seqs per wave
    const int col  = lane & 15;
    const int col8 = lane & 7;                   // clamped seq index for loads
    const int qd   = lane >> 4;
    const bool live = (col < 8);

    // ---- Whh A-frags (hi/lo), permuted rows, exp2-prescaled ----
    bf16x8 whhHi[6], whhLo[6];
    {
        const float* wsrc = Whh + d * 96 * 32;
        #pragma unroll
        for (int t = 0; t < 6; ++t) {
            const float sc = (t < 4) ? SR : SN;
            const int row = (t >> 1) * 32 + 8 * (col >> 2) + 4 * (t & 1) + (col & 3);
            const float* pr = wsrc + row * 32 + qd * 8;
            #pragma unroll
            for (int j = 0; j < 8; ++j) {
                float w = pr[j] * sc;
                unsigned short hi = f2bf(w);
                whhHi[t][j] = (short)hi;
                whhLo[t][j] = (short)f2bf(w - bf2f(hi));
            }
        }
    }

    // ---- Wih A-frags (hi only, permuted, prescaled) or L0 scalar weights ----
    bf16x8 wihF[6][2];
    float w0c[6][4], w1c[6][4];
    if constexpr (!IS_L0) {
        const float* wsrc = Wih + d * 96 * 64;
        #pragma unroll
        for (int t = 0; t < 6; ++t) {
            const float sc = (t < 4) ? SR : SN;
            const int row = (t >> 1) * 32 + 8 * (col >> 2) + 4 * (t & 1) + (col & 3);
            #pragma unroll
            for (int kc = 0; kc < 2; ++kc) {
                const float* pr = wsrc + row * 64 + kc * 32 + qd * 8;
                #pragma unroll
                for (int j = 0; j < 8; ++j) wihF[t][kc][j] = (short)f2bf(pr[j] * sc);
            }
        }
    } else {
        #pragma unroll
        for (int t = 0; t < 6; ++t) {
            const float sc = (t < 4) ? SR : SN;
            #pragma unroll
            for (int q = 0; q < 4; ++q) {
                const int row = (t >> 1) * 32 + 8 * qd + 4 * (t & 1) + q;
                const float* pr = Wih + d * 96 * 2 + row * 2;
                w0c[t][q] = pr[0] * sc;
                w1c[t][q] = pr[1] * sc;
            }
        }
    }

    // ---- biases as C-operand frags (prescaled) ----
    f32x4 biasIn[6], biasHN[2];
    {
        const float* bi = bih + d * 96;
        const float* bh = bhh + d * 96;
        #pragma unroll
        for (int t = 0; t < 4; ++t) {
            const int off = (t >> 1) * 32 + 8 * qd + 4 * (t & 1);
            float4 a = *(const float4*)(bi + off);
            float4 b = *(const float4*)(bh + off);
            biasIn[t][0] = (a.x + b.x) * SR; biasIn[t][1] = (a.y + b.y) * SR;
            biasIn[t][2] = (a.z + b.z) * SR; biasIn[t][3] = (a.w + b.w) * SR;
        }
        #pragma unroll
        for (int T = 0; T < 2; ++T) {
            const int off = 64 + 8 * qd + 4 * T;
            float4 a = *(const float4*)(bi + off);
            float4 b = *(const float4*)(bh + off);
            biasIn[4 + T][0] = a.x * SN; biasIn[4 + T][1] = a.y * SN;
            biasIn[4 + T][2] = a.z * SN; biasIn[4 + T][3] = a.w * SN;
            biasHN[T][0] = b.x * SN; biasHN[T][1] = b.y * SN;
            biasHN[T][2] = b.z * SN; biasHN[T][3] = b.w * SN;
        }
    }

    const int t0 = d ? (TT - 1) : 0;
    const int dt = d ? -1 : 1;

    bf16x8 hHi = {};
    float hprev[2][4] = {{0.f,0.f,0.f,0.f},{0.f,0.f,0.f,0.f}};

    // ---- one full GRU step (x regs in, h state updated, store h row) ----
    auto STEP = [&](uint4 xa, uint4 xb, float2 xs, unsigned short* outp) {
        f32x4 acc[6];
        if constexpr (!IS_L0) {
            bf16x8 a0 = __builtin_bit_cast(bf16x8, xa);
            bf16x8 a1 = __builtin_bit_cast(bf16x8, xb);
            #pragma unroll
            for (int t = 0; t < 6; ++t) {
                acc[t] = mfma16(wihF[t][0], a0, biasIn[t]);
                acc[t] = mfma16(wihF[t][1], a1, acc[t]);
            }
        } else {
            #pragma unroll
            for (int t = 0; t < 6; ++t)
                #pragma unroll
                for (int q = 0; q < 4; ++q)
                    acc[t][q] = fmaf(xs.x, w0c[t][q], fmaf(xs.y, w1c[t][q], biasIn[t][q]));
        }

        // ---- recurrence: (whhHi + whhLo) * hHi  (W precise, h bf16) ----
        #pragma unroll
        for (int t = 0; t < 4; ++t) {
            acc[t] = mfma16(whhHi[t], hHi, acc[t]);
            acc[t] = mfma16(whhLo[t], hHi, acc[t]);
        }
        f32x4 accHN[2];
        #pragma unroll
        for (int T = 0; T < 2; ++T) {
            accHN[T] = mfma16(whhHi[4 + T], hHi, biasHN[T]);
            accHN[T] = mfma16(whhLo[4 + T], hHi, accHN[T]);
        }

        unsigned int hw[4];
        #pragma unroll
        for (int T = 0; T < 2; ++T) {
            float h0 = hprev[T][0], h1 = hprev[T][1];
            float h2 = hprev[T][2], h3 = hprev[T][3];
            gate_pair(acc[T][0], acc[T][1], acc[2 + T][0], acc[2 + T][1],
                      acc[4 + T][0], acc[4 + T][1], accHN[T][0], accHN[T][1], h0, h1);
            gate_pair(acc[T][2], acc[T][3], acc[2 + T][2], acc[2 + T][3],
                      acc[4 + T][2], acc[4 + T][3], accHN[T][2], accHN[T][3], h2, h3);
            hprev[T][0] = h0; hprev[T][1] = h1; hprev[T][2] = h2; hprev[T][3] = h3;
            hw[2 * T]     = cvt_pk(h0, h1);
            hw[2 * T + 1] = cvt_pk(h2, h3);
        }
        hHi = __builtin_bit_cast(bf16x8, *(uint4*)hw);
        if (live) *(uint4*)outp = *(uint4*)hw;
    };

    // ---- pointers: A = even steps, B = odd steps (loads use clamped col8) ----
    const unsigned short* xptrA = nullptr; const unsigned short* xptrB = nullptr;
    const float* xfpA = nullptr; const float* xfpB = nullptr;
    uint4 xA0 = {}, xA1 = {}, xB0 = {}, xB1 = {};
    float2 xsA = {}, xsB = {};
    if constexpr (!IS_L0) {
        xptrA = bin + ((size_t)(b0 + col8) * TT + t0) * 64 + qd * 8;
        xptrB = xptrA + dt * 64;
        xA0 = *(const uint4*)xptrA; xA1 = *(const uint4*)(xptrA + 32);
        xB0 = *(const uint4*)xptrB; xB1 = *(const uint4*)(xptrB + 32);
    } else {
        xfpA = x0 + ((size_t)(b0 + col8) * TT + t0) * 2;
        xfpB = xfpA + dt * 2;
        xsA = *(const float2*)xfpA;
        xsB = *(const float2*)xfpB;
    }
    unsigned short* optrA = bout + ((size_t)(b0 + col8) * TT + t0) * 64 + d * 32 + qd * 8;
    unsigned short* optrB = optrA + dt * 64;

    for (int k = 0; k < 31; ++k) {            // steps 0..61, prefetch 2..63
        STEP(xA0, xA1, xsA, optrA); optrA += dt * 128;
        if constexpr (!IS_L0) {
            xptrA += dt * 128;
            xA0 = *(const uint4*)xptrA; xA1 = *(const uint4*)(xptrA + 32);
        } else {
            xfpA += dt * 4; xsA = *(const float2*)xfpA;
        }
        STEP(xB0, xB1, xsB, optrB); optrB += dt * 128;
        if constexpr (!IS_L0) {
            xptrB += dt * 128;
            xB0 = *(const uint4*)xptrB; xB1 = *(const uint4*)(xptrB + 32);
        } else {
            xfpB += dt * 4; xsB = *(const float2*)xfpB;
        }
    }
    STEP(xA0, xA1, xsA, optrA);               // s = 62
    STEP(xB0, xB1, xsB, optrB);               // s = 63
}

__global__ __launch_bounds__(256)
void fc_kernel(const unsigned short* __restrict__ bin,
               const float* __restrict__ Wfc,
               const float* __restrict__ bfc,
               float* __restrict__ out)
{
    __shared__ float sw[128];
    __shared__ float sb[2];
    const int tid = threadIdx.x;
    if (tid < 128) sw[tid] = Wfc[tid];
    if (tid < 2) sb[tid] = bfc[tid];
    __syncthreads();

    const size_t uidx = (size_t)blockIdx.x * 256 + tid;
    const unsigned short* ip = bin + uidx * 64;
    float a0 = sb[0], a1 = sb[1];
    #pragma unroll
    for (int i = 0; i < 64; i += 8) {
        uint4 raw = *(const uint4*)(ip + i);
        #pragma unroll
        for (int w = 0; w < 4; ++w) {
            unsigned int uu = ((const unsigned int*)&raw)[w];
            float f0 = __uint_as_float(uu << 16);
            float f1 = __uint_as_float(uu & 0xffff0000u);
            a0 = fmaf(f0, sw[i + 2 * w], a0);
            a1 = fmaf(f0, sw[64 + i + 2 * w], a1);
            a0 = fmaf(f1, sw[i + 2 * w + 1], a0);
            a1 = fmaf(f1, sw[64 + i + 2 * w + 1], a1);
        }
    }
    float2 o;
    o.x = tanh_fast(a0);
    o.y = tanh_fast(a1);
    *(float2*)&out[2 * uidx] = o;
}

extern "C" void kernel_launch(void* const* d_in, const int* in_sizes, int n_in,
                              void* d_out, int out_size, void* d_ws, size_t ws_size,
                              hipStream_t stream)
{
    const float* x    = (const float*)d_in[0];
    const float* Wih0 = (const float*)d_in[1];
    const float* Whh0 = (const float*)d_in[2];
    const float* bih0 = (const float*)d_in[3];
    const float* bhh0 = (const float*)d_in[4];
    const float* WihL = (const float*)d_in[5];
    const float* WhhL = (const float*)d_in[6];
    const float* bihL = (const float*)d_in[7];
    const float* bhhL = (const float*)d_in[8];
    const float* Wfc  = (const float*)d_in[9];
    const float* bfc  = (const float*)d_in[10];

    unsigned short* buf0 = (unsigned short*)d_ws;
    unsigned short* buf1 = buf0 + (size_t)BB * TT * 64;
    float* out = (float*)d_out;

    gru_mfma<true><<<1024, 256, 0, stream>>>(
        x, nullptr, Wih0, Whh0, bih0, bhh0, buf0);
    gru_mfma<false><<<1024, 256, 0, stream>>>(
        nullptr, buf0, WihL, WhhL, bihL, bhhL, buf1);
    gru_mfma<false><<<1024, 256, 0, stream>>>(
        nullptr, buf1, WihL + 2 * 96 * 64, WhhL + 2 * 96 * 32,
        bihL + 2 * 96, bhhL + 2 * 96, buf0);
    fc_kernel<<<(BB * TT) / 256, 256, 0, stream>>>(buf0, Wfc, bfc, out);
}

// Round 9
// 556.737 us; speedup vs baseline: 3.6596x; 3.6596x over previous
//
#include <hip/hip_runtime.h>
#include <cstdint>
#include <cstddef>

// GRU B=16384 T=64 H=32, 3 bidir layers + FC(64->2) + tanh.
// R8: R7's 8-seq/wave decomposition (4096 waves) with the register cap
// reverted to __launch_bounds__(256,2). R7's (256,4) forced a 64-VGPR cap ->
// scratch spills (FETCH 131MB->2.3GB, 43GB/s dispatches). At ~128 VGPRs the
// HW itself allows 4 waves/SIMD; the 4096-wave grid now fills them.
// Structure: permuted gate rows (D-frag==B-frag), zero LDS, exp2-folded
// weights, shared rcp, cvt_pk, 2x unroll, rec=(whhHi+whhLo)*hHi.

#define BB 16384
#define TT 64

typedef __attribute__((ext_vector_type(8))) short bf16x8;
typedef __attribute__((ext_vector_type(4))) float f32x4;

#if __has_builtin(__builtin_amdgcn_exp2f)
#define EXP2(x) __builtin_amdgcn_exp2f(x)
#else
#define EXP2(x) exp2f(x)
#endif
#if __has_builtin(__builtin_amdgcn_rcpf)
#define RCP(x) __builtin_amdgcn_rcpf(x)
#else
#define RCP(x) (1.0f / (x))
#endif

#define SR (-1.4426950408889634f)   // -log2(e)   for r,z gates
#define SN (-2.8853900817779268f)   // -2*log2(e) for n gate

__device__ __forceinline__ float tanh_fast(float x) { return 2.0f / (1.0f + __expf(-2.0f * x)) - 1.0f; }
__device__ __forceinline__ unsigned short f2bf(float f) {
    unsigned int u = __float_as_uint(f);
    u = u + 0x7fffu + ((u >> 16) & 1u);
    return (unsigned short)(u >> 16);
}
__device__ __forceinline__ float bf2f(unsigned short b) {
    return __uint_as_float(((unsigned int)b) << 16);
}
__device__ __forceinline__ unsigned int cvt_pk(float a, float b) {
#if __has_builtin(__builtin_amdgcn_cvt_pk_bf16_f32)
    typedef __bf16 bf16x2_t __attribute__((ext_vector_type(2)));
    bf16x2_t p = __builtin_amdgcn_cvt_pk_bf16_f32(a, b);
    return __builtin_bit_cast(unsigned int, p);
#else
    unsigned int ua = __float_as_uint(a), ub = __float_as_uint(b);
    unsigned int ha = (ua + 0x7fffu + ((ua >> 16) & 1u)) >> 16;
    unsigned int hb = (ub + 0x7fffu + ((ub >> 16) & 1u)) & 0xffff0000u;
    return ha | hb;
#endif
}
__device__ __forceinline__ f32x4 mfma16(bf16x8 a, bf16x8 b, f32x4 c) {
    return __builtin_amdgcn_mfma_f32_16x16x32_bf16(a, b, c, 0, 0, 0);
}

// Gates for a q-pair. Inputs are exp2-prescaled preactivations (C carried bias).
// sigma(x) = rcp(1+exp2(SR*x)); tanh(v) = 2*rcp(1+exp2(SN*v)) - 1.
__device__ __forceinline__ void gate_pair(float aR0, float aR1, float aZ0, float aZ1,
                                          float xN0, float xN1, float hN0, float hN1,
                                          float& hp0, float& hp1) {
    float er0 = EXP2(aR0), er1 = EXP2(aR1);
    float ez0 = EXP2(aZ0), ez1 = EXP2(aZ1);
    float Ar0 = 1.f + er0, Ar1 = 1.f + er1;
    float Az0 = 1.f + ez0, Az1 = 1.f + ez1;
    float iR = RCP(Ar0 * Ar1);
    float iZ = RCP(Az0 * Az1);
    float r0 = iR * Ar1, r1 = iR * Ar0;
    float z0 = iZ * Az1, z1 = iZ * Az0;
    float v0 = fmaf(r0, hN0, xN0), v1 = fmaf(r1, hN1, xN1);
    float en0 = EXP2(v0), en1 = EXP2(v1);
    float An0 = 1.f + en0, An1 = 1.f + en1;
    float iN = RCP(An0 * An1);
    float n0 = fmaf(2.f, iN * An1, -1.f);
    float n1 = fmaf(2.f, iN * An0, -1.f);
    hp0 = fmaf(z0, hp0 - n0, n0);
    hp1 = fmaf(z1, hp1 - n1, n1);
}

// A: lane = A[m=lane&15][k=(lane>>4)*8+j]   B: lane = B[k=(lane>>4)*8+j][n=lane&15]
// D: lane = D[row=(lane>>4)*4+reg][col=lane&15]
// Gate-row permutation: block row position (T*16 + qd*4 + q) <- original unit 8qd+4T+q.

template<bool IS_L0>
__global__ __launch_bounds__(256, 2)
void gru_mfma(const float* __restrict__ x0,
              const unsigned short* __restrict__ bin,
              const float* __restrict__ Wih,               // (2,96,I)
              const float* __restrict__ Whh,               // (2,96,32)
              const float* __restrict__ bih,               // (2,96)
              const float* __restrict__ bhh,               // (2,96)
              unsigned short* __restrict__ bout)           // (B,T,64) bf16
{
    const int tid  = threadIdx.x;
    const int lane = tid & 63;
    const int wv   = tid >> 6;
    const int g    = blockIdx.x * 4 + wv;        // 0..4095
    const int d    = g >> 11;
    const int b0   = (g & 2047) * 8;             // 8 seqs per wave
    const int col  = lane & 15;
    const int col8 = lane & 7;                   // clamped seq index for loads
    const int qd   = lane >> 4;
    const bool live = (col < 8);

    // ---- Whh A-frags (hi/lo), permuted rows, exp2-prescaled ----
    bf16x8 whhHi[6], whhLo[6];
    {
        const float* wsrc = Whh + d * 96 * 32;
        #pragma unroll
        for (int t = 0; t < 6; ++t) {
            const float sc = (t < 4) ? SR : SN;
            const int row = (t >> 1) * 32 + 8 * (col >> 2) + 4 * (t & 1) + (col & 3);
            const float* pr = wsrc + row * 32 + qd * 8;
            #pragma unroll
            for (int j = 0; j < 8; ++j) {
                float w = pr[j] * sc;
                unsigned short hi = f2bf(w);
                whhHi[t][j] = (short)hi;
                whhLo[t][j] = (short)f2bf(w - bf2f(hi));
            }
        }
    }

    // ---- Wih A-frags (hi only, permuted, prescaled) or L0 scalar weights ----
    bf16x8 wihF[6][2];
    float w0c[6][4], w1c[6][4];
    if constexpr (!IS_L0) {
        const float* wsrc = Wih + d * 96 * 64;
        #pragma unroll
        for (int t = 0; t < 6; ++t) {
            const float sc = (t < 4) ? SR : SN;
            const int row = (t >> 1) * 32 + 8 * (col >> 2) + 4 * (t & 1) + (col & 3);
            #pragma unroll
            for (int kc = 0; kc < 2; ++kc) {
                const float* pr = wsrc + row * 64 + kc * 32 + qd * 8;
                #pragma unroll
                for (int j = 0; j < 8; ++j) wihF[t][kc][j] = (short)f2bf(pr[j] * sc);
            }
        }
    } else {
        #pragma unroll
        for (int t = 0; t < 6; ++t) {
            const float sc = (t < 4) ? SR : SN;
            #pragma unroll
            for (int q = 0; q < 4; ++q) {
                const int row = (t >> 1) * 32 + 8 * qd + 4 * (t & 1) + q;
                const float* pr = Wih + d * 96 * 2 + row * 2;
                w0c[t][q] = pr[0] * sc;
                w1c[t][q] = pr[1] * sc;
            }
        }
    }

    // ---- biases as C-operand frags (prescaled) ----
    f32x4 biasIn[6], biasHN[2];
    {
        const float* bi = bih + d * 96;
        const float* bh = bhh + d * 96;
        #pragma unroll
        for (int t = 0; t < 4; ++t) {
            const int off = (t >> 1) * 32 + 8 * qd + 4 * (t & 1);
            float4 a = *(const float4*)(bi + off);
            float4 b = *(const float4*)(bh + off);
            biasIn[t][0] = (a.x + b.x) * SR; biasIn[t][1] = (a.y + b.y) * SR;
            biasIn[t][2] = (a.z + b.z) * SR; biasIn[t][3] = (a.w + b.w) * SR;
        }
        #pragma unroll
        for (int T = 0; T < 2; ++T) {
            const int off = 64 + 8 * qd + 4 * T;
            float4 a = *(const float4*)(bi + off);
            float4 b = *(const float4*)(bh + off);
            biasIn[4 + T][0] = a.x * SN; biasIn[4 + T][1] = a.y * SN;
            biasIn[4 + T][2] = a.z * SN; biasIn[4 + T][3] = a.w * SN;
            biasHN[T][0] = b.x * SN; biasHN[T][1] = b.y * SN;
            biasHN[T][2] = b.z * SN; biasHN[T][3] = b.w * SN;
        }
    }

    const int t0 = d ? (TT - 1) : 0;
    const int dt = d ? -1 : 1;

    bf16x8 hHi = {};
    float hprev[2][4] = {{0.f,0.f,0.f,0.f},{0.f,0.f,0.f,0.f}};

    // ---- one full GRU step (x regs in, h state updated, store h row) ----
    auto STEP = [&](uint4 xa, uint4 xb, float2 xs, unsigned short* outp) {
        f32x4 acc[6];
        if constexpr (!IS_L0) {
            bf16x8 a0 = __builtin_bit_cast(bf16x8, xa);
            bf16x8 a1 = __builtin_bit_cast(bf16x8, xb);
            #pragma unroll
            for (int t = 0; t < 6; ++t) {
                acc[t] = mfma16(wihF[t][0], a0, biasIn[t]);
                acc[t] = mfma16(wihF[t][1], a1, acc[t]);
            }
        } else {
            #pragma unroll
            for (int t = 0; t < 6; ++t)
                #pragma unroll
                for (int q = 0; q < 4; ++q)
                    acc[t][q] = fmaf(xs.x, w0c[t][q], fmaf(xs.y, w1c[t][q], biasIn[t][q]));
        }

        // ---- recurrence: (whhHi + whhLo) * hHi  (W precise, h bf16) ----
        #pragma unroll
        for (int t = 0; t < 4; ++t) {
            acc[t] = mfma16(whhHi[t], hHi, acc[t]);
            acc[t] = mfma16(whhLo[t], hHi, acc[t]);
        }
        f32x4 accHN[2];
        #pragma unroll
        for (int T = 0; T < 2; ++T) {
            accHN[T] = mfma16(whhHi[4 + T], hHi, biasHN[T]);
            accHN[T] = mfma16(whhLo[4 + T], hHi, accHN[T]);
        }

        unsigned int hw[4];
        #pragma unroll
        for (int T = 0; T < 2; ++T) {
            float h0 = hprev[T][0], h1 = hprev[T][1];
            float h2 = hprev[T][2], h3 = hprev[T][3];
            gate_pair(acc[T][0], acc[T][1], acc[2 + T][0], acc[2 + T][1],
                      acc[4 + T][0], acc[4 + T][1], accHN[T][0], accHN[T][1], h0, h1);
            gate_pair(acc[T][2], acc[T][3], acc[2 + T][2], acc[2 + T][3],
                      acc[4 + T][2], acc[4 + T][3], accHN[T][2], accHN[T][3], h2, h3);
            hprev[T][0] = h0; hprev[T][1] = h1; hprev[T][2] = h2; hprev[T][3] = h3;
            hw[2 * T]     = cvt_pk(h0, h1);
            hw[2 * T + 1] = cvt_pk(h2, h3);
        }
        hHi = __builtin_bit_cast(bf16x8, *(uint4*)hw);
        if (live) *(uint4*)outp = *(uint4*)hw;
    };

    // ---- pointers: A = even steps, B = odd steps (loads use clamped col8) ----
    const unsigned short* xptrA = nullptr; const unsigned short* xptrB = nullptr;
    const float* xfpA = nullptr; const float* xfpB = nullptr;
    uint4 xA0 = {}, xA1 = {}, xB0 = {}, xB1 = {};
    float2 xsA = {}, xsB = {};
    if constexpr (!IS_L0) {
        xptrA = bin + ((size_t)(b0 + col8) * TT + t0) * 64 + qd * 8;
        xptrB = xptrA + dt * 64;
        xA0 = *(const uint4*)xptrA; xA1 = *(const uint4*)(xptrA + 32);
        xB0 = *(const uint4*)xptrB; xB1 = *(const uint4*)(xptrB + 32);
    } else {
        xfpA = x0 + ((size_t)(b0 + col8) * TT + t0) * 2;
        xfpB = xfpA + dt * 2;
        xsA = *(const float2*)xfpA;
        xsB = *(const float2*)xfpB;
    }
    unsigned short* optrA = bout + ((size_t)(b0 + col8) * TT + t0) * 64 + d * 32 + qd * 8;
    unsigned short* optrB = optrA + dt * 64;

    for (int k = 0; k < 31; ++k) {            // steps 0..61, prefetch 2..63
        STEP(xA0, xA1, xsA, optrA); optrA += dt * 128;
        if constexpr (!IS_L0) {
            xptrA += dt * 128;
            xA0 = *(const uint4*)xptrA; xA1 = *(const uint4*)(xptrA + 32);
        } else {
            xfpA += dt * 4; xsA = *(const float2*)xfpA;
        }
        STEP(xB0, xB1, xsB, optrB); optrB += dt * 128;
        if constexpr (!IS_L0) {
            xptrB += dt * 128;
            xB0 = *(const uint4*)xptrB; xB1 = *(const uint4*)(xptrB + 32);
        } else {
            xfpB += dt * 4; xsB = *(const float2*)xfpB;
        }
    }
    STEP(xA0, xA1, xsA, optrA);               // s = 62
    STEP(xB0, xB1, xsB, optrB);               // s = 63
}

__global__ __launch_bounds__(256)
void fc_kernel(const unsigned short* __restrict__ bin,
               const float* __restrict__ Wfc,
               const float* __restrict__ bfc,
               float* __restrict__ out)
{
    __shared__ float sw[128];
    __shared__ float sb[2];
    const int tid = threadIdx.x;
    if (tid < 128) sw[tid] = Wfc[tid];
    if (tid < 2) sb[tid] = bfc[tid];
    __syncthreads();

    const size_t uidx = (size_t)blockIdx.x * 256 + tid;
    const unsigned short* ip = bin + uidx * 64;
    float a0 = sb[0], a1 = sb[1];
    #pragma unroll
    for (int i = 0; i < 64; i += 8) {
        uint4 raw = *(const uint4*)(ip + i);
        #pragma unroll
        for (int w = 0; w < 4; ++w) {
            unsigned int uu = ((const unsigned int*)&raw)[w];
            float f0 = __uint_as_float(uu << 16);
            float f1 = __uint_as_float(uu & 0xffff0000u);
            a0 = fmaf(f0, sw[i + 2 * w], a0);
            a1 = fmaf(f0, sw[64 + i + 2 * w], a1);
            a0 = fmaf(f1, sw[i + 2 * w + 1], a0);
            a1 = fmaf(f1, sw[64 + i + 2 * w + 1], a1);
        }
    }
    float2 o;
    o.x = tanh_fast(a0);
    o.y = tanh_fast(a1);
    *(float2*)&out[2 * uidx] = o;
}

extern "C" void kernel_launch(void* const* d_in, const int* in_sizes, int n_in,
                              void* d_out, int out_size, void* d_ws, size_t ws_size,
                              hipStream_t stream)
{
    const float* x    = (const float*)d_in[0];
    const float* Wih0 = (const float*)d_in[1];
    const float* Whh0 = (const float*)d_in[2];
    const float* bih0 = (const float*)d_in[3];
    const float* bhh0 = (const float*)d_in[4];
    const float* WihL = (const float*)d_in[5];
    const float* WhhL = (const float*)d_in[6];
    const float* bihL = (const float*)d_in[7];
    const float* bhhL = (const float*)d_in[8];
    const float* Wfc  = (const float*)d_in[9];
    const float* bfc  = (const float*)d_in[10];

    unsigned short* buf0 = (unsigned short*)d_ws;
    unsigned short* buf1 = buf0 + (size_t)BB * TT * 64;
    float* out = (float*)d_out;

    gru_mfma<true><<<1024, 256, 0, stream>>>(
        x, nullptr, Wih0, Whh0, bih0, bhh0, buf0);
    gru_mfma<false><<<1024, 256, 0, stream>>>(
        nullptr, buf0, WihL, WhhL, bihL, bhhL, buf1);
    gru_mfma<false><<<1024, 256, 0, stream>>>(
        nullptr, buf1, WihL + 2 * 96 * 64, WhhL + 2 * 96 * 32,
        bihL + 2 * 96, bhhL + 2 * 96, buf0);
    fc_kernel<<<(BB * TT) / 256, 256, 0, stream>>>(buf0, Wfc, bfc, out);
}

// Round 10
// 364.250 us; speedup vs baseline: 5.5936x; 1.5284x over previous
//
#include <hip/hip_runtime.h>
#include <cstdint>
#include <cstddef>

// GRU B=16384 T=64 H=32, 3 bidir layers + FC(64->2) + tanh.
// R9: R6 decomposition (16 seqs/wave, 2048 waves, permuted gate rows so
// D-frag==B-frag, zero LDS, exp2-folded weights, shared rcp, cvt_pk) with
// intra-wave software pipelining: the 12 input-projection MFMAs for step s+1
// (h-independent) are issued BEFORE the gate VALU of step s, so each wave's
// gate phase overlaps its own matrix-pipe work instead of idling it.
// rec = (whhHi+whhLo)*hHi (W fp32-precise via hi+lo bf16, h bf16, fp32 hprev).

#define BB 16384
#define TT 64

typedef __attribute__((ext_vector_type(8))) short bf16x8;
typedef __attribute__((ext_vector_type(4))) float f32x4;

#if __has_builtin(__builtin_amdgcn_exp2f)
#define EXP2(x) __builtin_amdgcn_exp2f(x)
#else
#define EXP2(x) exp2f(x)
#endif
#if __has_builtin(__builtin_amdgcn_rcpf)
#define RCP(x) __builtin_amdgcn_rcpf(x)
#else
#define RCP(x) (1.0f / (x))
#endif

#define SR (-1.4426950408889634f)   // -log2(e)   for r,z gates
#define SN (-2.8853900817779268f)   // -2*log2(e) for n gate

__device__ __forceinline__ float tanh_fast(float x) { return 2.0f / (1.0f + __expf(-2.0f * x)) - 1.0f; }
__device__ __forceinline__ unsigned short f2bf(float f) {
    unsigned int u = __float_as_uint(f);
    u = u + 0x7fffu + ((u >> 16) & 1u);
    return (unsigned short)(u >> 16);
}
__device__ __forceinline__ float bf2f(unsigned short b) {
    return __uint_as_float(((unsigned int)b) << 16);
}
__device__ __forceinline__ unsigned int cvt_pk(float a, float b) {
#if __has_builtin(__builtin_amdgcn_cvt_pk_bf16_f32)
    typedef __bf16 bf16x2_t __attribute__((ext_vector_type(2)));
    bf16x2_t p = __builtin_amdgcn_cvt_pk_bf16_f32(a, b);
    return __builtin_bit_cast(unsigned int, p);
#else
    unsigned int ua = __float_as_uint(a), ub = __float_as_uint(b);
    unsigned int ha = (ua + 0x7fffu + ((ua >> 16) & 1u)) >> 16;
    unsigned int hb = (ub + 0x7fffu + ((ub >> 16) & 1u)) & 0xffff0000u;
    return ha | hb;
#endif
}
__device__ __forceinline__ f32x4 mfma16(bf16x8 a, bf16x8 b, f32x4 c) {
    return __builtin_amdgcn_mfma_f32_16x16x32_bf16(a, b, c, 0, 0, 0);
}

// Gates for a q-pair. Inputs are exp2-prescaled preactivations (C carried bias).
// sigma(x) = rcp(1+exp2(SR*x)); tanh(v) = 2*rcp(1+exp2(SN*v)) - 1.
__device__ __forceinline__ void gate_pair(float aR0, float aR1, float aZ0, float aZ1,
                                          float xN0, float xN1, float hN0, float hN1,
                                          float& hp0, float& hp1) {
    float er0 = EXP2(aR0), er1 = EXP2(aR1);
    float ez0 = EXP2(aZ0), ez1 = EXP2(aZ1);
    float Ar0 = 1.f + er0, Ar1 = 1.f + er1;
    float Az0 = 1.f + ez0, Az1 = 1.f + ez1;
    float iR = RCP(Ar0 * Ar1);
    float iZ = RCP(Az0 * Az1);
    float r0 = iR * Ar1, r1 = iR * Ar0;
    float z0 = iZ * Az1, z1 = iZ * Az0;
    float v0 = fmaf(r0, hN0, xN0), v1 = fmaf(r1, hN1, xN1);
    float en0 = EXP2(v0), en1 = EXP2(v1);
    float An0 = 1.f + en0, An1 = 1.f + en1;
    float iN = RCP(An0 * An1);
    float n0 = fmaf(2.f, iN * An1, -1.f);
    float n1 = fmaf(2.f, iN * An0, -1.f);
    hp0 = fmaf(z0, hp0 - n0, n0);
    hp1 = fmaf(z1, hp1 - n1, n1);
}

// A: lane = A[m=lane&15][k=(lane>>4)*8+j]   B: lane = B[k=(lane>>4)*8+j][n=lane&15]
// D: lane = D[row=(lane>>4)*4+reg][col=lane&15]
// Gate-row permutation: block row position (T*16 + qd*4 + q) <- original unit 8qd+4T+q.

template<bool IS_L0>
__global__ __launch_bounds__(256, 2)
void gru_mfma(const float* __restrict__ x0,
              const unsigned short* __restrict__ bin,
              const float* __restrict__ Wih,               // (2,96,I)
              const float* __restrict__ Whh,               // (2,96,32)
              const float* __restrict__ bih,               // (2,96)
              const float* __restrict__ bhh,               // (2,96)
              unsigned short* __restrict__ bout)           // (B,T,64) bf16
{
    const int tid  = threadIdx.x;
    const int lane = tid & 63;
    const int wv   = tid >> 6;
    const int g    = blockIdx.x * 4 + wv;        // 0..2047
    const int d    = g >> 10;
    const int b0   = (g & 1023) * 16;            // 16 seqs per wave
    const int col  = lane & 15;
    const int qd   = lane >> 4;

    // ---- Whh A-frags (hi/lo), permuted rows, exp2-prescaled ----
    bf16x8 whhHi[6], whhLo[6];
    {
        const float* wsrc = Whh + d * 96 * 32;
        #pragma unroll
        for (int t = 0; t < 6; ++t) {
            const float sc = (t < 4) ? SR : SN;
            const int row = (t >> 1) * 32 + 8 * (col >> 2) + 4 * (t & 1) + (col & 3);
            const float* pr = wsrc + row * 32 + qd * 8;
            #pragma unroll
            for (int j = 0; j < 8; ++j) {
                float w = pr[j] * sc;
                unsigned short hi = f2bf(w);
                whhHi[t][j] = (short)hi;
                whhLo[t][j] = (short)f2bf(w - bf2f(hi));
            }
        }
    }

    // ---- Wih A-frags (hi only, permuted, prescaled) or L0 scalar weights ----
    bf16x8 wihF[6][2];
    float w0c[6][4], w1c[6][4];
    if constexpr (!IS_L0) {
        const float* wsrc = Wih + d * 96 * 64;
        #pragma unroll
        for (int t = 0; t < 6; ++t) {
            const float sc = (t < 4) ? SR : SN;
            const int row = (t >> 1) * 32 + 8 * (col >> 2) + 4 * (t & 1) + (col & 3);
            #pragma unroll
            for (int kc = 0; kc < 2; ++kc) {
                const float* pr = wsrc + row * 64 + kc * 32 + qd * 8;
                #pragma unroll
                for (int j = 0; j < 8; ++j) wihF[t][kc][j] = (short)f2bf(pr[j] * sc);
            }
        }
    } else {
        #pragma unroll
        for (int t = 0; t < 6; ++t) {
            const float sc = (t < 4) ? SR : SN;
            #pragma unroll
            for (int q = 0; q < 4; ++q) {
                const int row = (t >> 1) * 32 + 8 * qd + 4 * (t & 1) + q;
                const float* pr = Wih + d * 96 * 2 + row * 2;
                w0c[t][q] = pr[0] * sc;
                w1c[t][q] = pr[1] * sc;
            }
        }
    }

    // ---- biases as C-operand frags (prescaled) ----
    f32x4 biasIn[6], biasHN[2];
    {
        const float* bi = bih + d * 96;
        const float* bh = bhh + d * 96;
        #pragma unroll
        for (int t = 0; t < 4; ++t) {
            const int off = (t >> 1) * 32 + 8 * qd + 4 * (t & 1);
            float4 a = *(const float4*)(bi + off);
            float4 b = *(const float4*)(bh + off);
            biasIn[t][0] = (a.x + b.x) * SR; biasIn[t][1] = (a.y + b.y) * SR;
            biasIn[t][2] = (a.z + b.z) * SR; biasIn[t][3] = (a.w + b.w) * SR;
        }
        #pragma unroll
        for (int T = 0; T < 2; ++T) {
            const int off = 64 + 8 * qd + 4 * T;
            float4 a = *(const float4*)(bi + off);
            float4 b = *(const float4*)(bh + off);
            biasIn[4 + T][0] = a.x * SN; biasIn[4 + T][1] = a.y * SN;
            biasIn[4 + T][2] = a.z * SN; biasIn[4 + T][3] = a.w * SN;
            biasHN[T][0] = b.x * SN; biasHN[T][1] = b.y * SN;
            biasHN[T][2] = b.z * SN; biasHN[T][3] = b.w * SN;
        }
    }

    const int t0 = d ? (TT - 1) : 0;
    const int dt = d ? -1 : 1;

    bf16x8 hHi = {};
    float hprev[2][4] = {{0.f,0.f,0.f,0.f},{0.f,0.f,0.f,0.f}};

    // ---- recurrence MFMAs onto acc (needs current hHi) ----
    auto REC = [&](f32x4 (&acc)[6], f32x4 (&accHN)[2]) {
        #pragma unroll
        for (int t = 0; t < 4; ++t) {
            acc[t] = mfma16(whhHi[t], hHi, acc[t]);
            acc[t] = mfma16(whhLo[t], hHi, acc[t]);
        }
        #pragma unroll
        for (int T = 0; T < 2; ++T) {
            accHN[T] = mfma16(whhHi[4 + T], hHi, biasHN[T]);
            accHN[T] = mfma16(whhLo[4 + T], hHi, accHN[T]);
        }
    };

    // ---- next step's input projection (h-independent; overlaps gate VALU) ----
    auto PROJ = [&](f32x4 (&accN)[6], uint4 nx0, uint4 nx1, float2 nxs) {
        if constexpr (!IS_L0) {
            bf16x8 a0 = __builtin_bit_cast(bf16x8, nx0);
            bf16x8 a1 = __builtin_bit_cast(bf16x8, nx1);
            #pragma unroll
            for (int t = 0; t < 6; ++t) {
                accN[t] = mfma16(wihF[t][0], a0, biasIn[t]);
                accN[t] = mfma16(wihF[t][1], a1, accN[t]);
            }
        } else {
            #pragma unroll
            for (int t = 0; t < 6; ++t)
                #pragma unroll
                for (int q = 0; q < 4; ++q)
                    accN[t][q] = fmaf(nxs.x, w0c[t][q], fmaf(nxs.y, w1c[t][q], biasIn[t][q]));
        }
    };

    // ---- gates + pack + store; updates hHi ----
    auto GATES = [&](f32x4 (&acc)[6], f32x4 (&accHN)[2], unsigned short* outp) {
        unsigned int hw[4];
        #pragma unroll
        for (int T = 0; T < 2; ++T) {
            float h0 = hprev[T][0], h1 = hprev[T][1];
            float h2 = hprev[T][2], h3 = hprev[T][3];
            gate_pair(acc[T][0], acc[T][1], acc[2 + T][0], acc[2 + T][1],
                      acc[4 + T][0], acc[4 + T][1], accHN[T][0], accHN[T][1], h0, h1);
            gate_pair(acc[T][2], acc[T][3], acc[2 + T][2], acc[2 + T][3],
                      acc[4 + T][2], acc[4 + T][3], accHN[T][2], accHN[T][3], h2, h3);
            hprev[T][0] = h0; hprev[T][1] = h1; hprev[T][2] = h2; hprev[T][3] = h3;
            hw[2 * T]     = cvt_pk(h0, h1);
            hw[2 * T + 1] = cvt_pk(h2, h3);
        }
        hHi = __builtin_bit_cast(bf16x8, *(uint4*)hw);
        *(uint4*)outp = *(uint4*)hw;
    };

    // ---- x streams: even loads x[2k+2], odd loads x[2k+3] ----
    f32x4 accA[6], accB[6], accHN[2];
    uint4 xc0 = {}, xc1 = {}, xe0 = {}, xe1 = {};
    float2 xsc = {}, xse = {};
    const unsigned short* xptrE = nullptr; const unsigned short* xptrO = nullptr;
    const float* xfpE = nullptr; const float* xfpO = nullptr;

    if constexpr (!IS_L0) {
        const unsigned short* p0 = bin + ((size_t)(b0 + col) * TT + t0) * 64 + qd * 8;
        uint4 a = *(const uint4*)p0, b = *(const uint4*)(p0 + 32);
        PROJ(accA, a, b, {});                         // acc for step 0
        const unsigned short* p1 = p0 + dt * 64;
        xc0 = *(const uint4*)p1; xc1 = *(const uint4*)(p1 + 32);   // x[1]
        xptrE = p0 + dt * 128;                        // x[2]
        xptrO = p0 + dt * 192;                        // x[3]
    } else {
        const float* p0 = x0 + ((size_t)(b0 + col) * TT + t0) * 2;
        float2 xs0 = *(const float2*)p0;
        PROJ(accA, {}, {}, xs0);
        xsc = *(const float2*)(p0 + dt * 2);          // x[1]
        xfpE = p0 + dt * 4;                           // x[2]
        xfpO = p0 + dt * 6;                           // x[3]
    }
    unsigned short* optrA = bout + ((size_t)(b0 + col) * TT + t0) * 64 + d * 32 + qd * 8;
    unsigned short* optrB = optrA + dt * 64;

    for (int k = 0; k < 31; ++k) {                    // steps 0..61
        // prefetch x[2k+2]
        if constexpr (!IS_L0) {
            xe0 = *(const uint4*)xptrE; xe1 = *(const uint4*)(xptrE + 32);
            xptrE += dt * 128;
        } else { xse = *(const float2*)xfpE; xfpE += dt * 4; }
        // step 2k: rec on accA, project x[2k+1] into accB, then gates
        REC(accA, accHN);
        PROJ(accB, xc0, xc1, xsc);
        GATES(accA, accHN, optrA); optrA += dt * 128;
        // prefetch x[2k+3]
        if constexpr (!IS_L0) {
            xc0 = *(const uint4*)xptrO; xc1 = *(const uint4*)(xptrO + 32);
            xptrO += dt * 128;
        } else { xsc = *(const float2*)xfpO; xfpO += dt * 4; }
        // step 2k+1: rec on accB, project x[2k+2] into accA, then gates
        REC(accB, accHN);
        PROJ(accA, xe0, xe1, xse);
        GATES(accB, accHN, optrB); optrB += dt * 128;
    }
    // step 62: rec(accA), project x[63] into accB, gates
    REC(accA, accHN);
    PROJ(accB, xc0, xc1, xsc);
    GATES(accA, accHN, optrA);
    // step 63: rec(accB), gates (no further projection)
    REC(accB, accHN);
    GATES(accB, accHN, optrB);
}

__global__ __launch_bounds__(256)
void fc_kernel(const unsigned short* __restrict__ bin,
               const float* __restrict__ Wfc,
               const float* __restrict__ bfc,
               float* __restrict__ out)
{
    __shared__ float sw[128];
    __shared__ float sb[2];
    const int tid = threadIdx.x;
    if (tid < 128) sw[tid] = Wfc[tid];
    if (tid < 2) sb[tid] = bfc[tid];
    __syncthreads();

    const size_t uidx = (size_t)blockIdx.x * 256 + tid;
    const unsigned short* ip = bin + uidx * 64;
    float a0 = sb[0], a1 = sb[1];
    #pragma unroll
    for (int i = 0; i < 64; i += 8) {
        uint4 raw = *(const uint4*)(ip + i);
        #pragma unroll
        for (int w = 0; w < 4; ++w) {
            unsigned int uu = ((const unsigned int*)&raw)[w];
            float f0 = __uint_as_float(uu << 16);
            float f1 = __uint_as_float(uu & 0xffff0000u);
            a0 = fmaf(f0, sw[i + 2 * w], a0);
            a1 = fmaf(f0, sw[64 + i + 2 * w], a1);
            a0 = fmaf(f1, sw[i + 2 * w + 1], a0);
            a1 = fmaf(f1, sw[64 + i + 2 * w + 1], a1);
        }
    }
    float2 o;
    o.x = tanh_fast(a0);
    o.y = tanh_fast(a1);
    *(float2*)&out[2 * uidx] = o;
}

extern "C" void kernel_launch(void* const* d_in, const int* in_sizes, int n_in,
                              void* d_out, int out_size, void* d_ws, size_t ws_size,
                              hipStream_t stream)
{
    const float* x    = (const float*)d_in[0];
    const float* Wih0 = (const float*)d_in[1];
    const float* Whh0 = (const float*)d_in[2];
    const float* bih0 = (const float*)d_in[3];
    const float* bhh0 = (const float*)d_in[4];
    const float* WihL = (const float*)d_in[5];
    const float* WhhL = (const float*)d_in[6];
    const float* bihL = (const float*)d_in[7];
    const float* bhhL = (const float*)d_in[8];
    const float* Wfc  = (const float*)d_in[9];
    const float* bfc  = (const float*)d_in[10];

    unsigned short* buf0 = (unsigned short*)d_ws;
    unsigned short* buf1 = buf0 + (size_t)BB * TT * 64;
    float* out = (float*)d_out;

    gru_mfma<true><<<512, 256, 0, stream>>>(
        x, nullptr, Wih0, Whh0, bih0, bhh0, buf0);
    gru_mfma<false><<<512, 256, 0, stream>>>(
        nullptr, buf0, WihL, WhhL, bihL, bhhL, buf1);
    gru_mfma<false><<<512, 256, 0, stream>>>(
        nullptr, buf1, WihL + 2 * 96 * 64, WhhL + 2 * 96 * 32,
        bihL + 2 * 96, bhhL + 2 * 96, buf0);
    fc_kernel<<<(BB * TT) / 256, 256, 0, stream>>>(buf0, Wfc, bfc, out);
}

// Round 12
// 334.008 us; speedup vs baseline: 6.1000x; 1.0905x over previous
//
#include <hip/hip_runtime.h>
#include <cstdint>
#include <cstddef>

// GRU B=16384 T=64 H=32, 3 bidir layers + FC(64->2) + tanh.
// R11: R10 (full f16 datapath) with the cvt_pkrtz builtin type fixed
// (__fp16 vector return, bit_cast to u32). Whh/Wih single f16, h and
// inter-layer activations f16, fp32 accumulators. REC = 6 MFMAs, chain 1.
// Structure: 16 seqs/wave, permuted gate rows (D-frag==B-frag), zero LDS,
// exp2-folded weights, shared rcp, pipelined PROJ, 2x unroll.

#define BB 16384
#define TT 64

typedef __attribute__((ext_vector_type(8))) _Float16 f16x8;
typedef __attribute__((ext_vector_type(4))) float f32x4;

#if __has_builtin(__builtin_amdgcn_exp2f)
#define EXP2(x) __builtin_amdgcn_exp2f(x)
#else
#define EXP2(x) exp2f(x)
#endif
#if __has_builtin(__builtin_amdgcn_rcpf)
#define RCP(x) __builtin_amdgcn_rcpf(x)
#else
#define RCP(x) (1.0f / (x))
#endif

#define SR (-1.4426950408889634f)   // -log2(e)   for r,z gates
#define SN (-2.8853900817779268f)   // -2*log2(e) for n gate

__device__ __forceinline__ float tanh_fast(float x) { return 2.0f / (1.0f + __expf(-2.0f * x)) - 1.0f; }
__device__ __forceinline__ unsigned short f2h(float f) {
    _Float16 h = (_Float16)f;                      // RNE
    return __builtin_bit_cast(unsigned short, h);
}
// pack two f32 -> two f16 in one dword (v_cvt_pkrtz_f16_f32)
__device__ __forceinline__ unsigned int cvt_pkh(float a, float b) {
#if __has_builtin(__builtin_amdgcn_cvt_pkrtz)
    typedef __fp16 h2_t __attribute__((ext_vector_type(2)));
    h2_t p = __builtin_amdgcn_cvt_pkrtz(a, b);
    return __builtin_bit_cast(unsigned int, p);
#else
    return (unsigned int)f2h(a) | ((unsigned int)f2h(b) << 16);
#endif
}
__device__ __forceinline__ f32x4 mfma16h(f16x8 a, f16x8 b, f32x4 c) {
    return __builtin_amdgcn_mfma_f32_16x16x32_f16(a, b, c, 0, 0, 0);
}

// Gates for a q-pair. Inputs are exp2-prescaled preactivations (C carried bias).
// sigma(x) = rcp(1+exp2(SR*x)); tanh(v) = 2*rcp(1+exp2(SN*v)) - 1.
__device__ __forceinline__ void gate_pair(float aR0, float aR1, float aZ0, float aZ1,
                                          float xN0, float xN1, float hN0, float hN1,
                                          float& hp0, float& hp1) {
    float er0 = EXP2(aR0), er1 = EXP2(aR1);
    float ez0 = EXP2(aZ0), ez1 = EXP2(aZ1);
    float Ar0 = 1.f + er0, Ar1 = 1.f + er1;
    float Az0 = 1.f + ez0, Az1 = 1.f + ez1;
    float iR = RCP(Ar0 * Ar1);
    float iZ = RCP(Az0 * Az1);
    float r0 = iR * Ar1, r1 = iR * Ar0;
    float z0 = iZ * Az1, z1 = iZ * Az0;
    float v0 = fmaf(r0, hN0, xN0), v1 = fmaf(r1, hN1, xN1);
    float en0 = EXP2(v0), en1 = EXP2(v1);
    float An0 = 1.f + en0, An1 = 1.f + en1;
    float iN = RCP(An0 * An1);
    float n0 = fmaf(2.f, iN * An1, -1.f);
    float n1 = fmaf(2.f, iN * An0, -1.f);
    hp0 = fmaf(z0, hp0 - n0, n0);
    hp1 = fmaf(z1, hp1 - n1, n1);
}

// A: lane = A[m=lane&15][k=(lane>>4)*8+j]   B: lane = B[k=(lane>>4)*8+j][n=lane&15]
// D: lane = D[row=(lane>>4)*4+reg][col=lane&15]
// Gate-row permutation: block row position (T*16 + qd*4 + q) <- original unit 8qd+4T+q.

template<bool IS_L0>
__global__ __launch_bounds__(256, 2)
void gru_mfma(const float* __restrict__ x0,
              const unsigned short* __restrict__ bin,      // f16 bits (B,T,64)
              const float* __restrict__ Wih,               // (2,96,I)
              const float* __restrict__ Whh,               // (2,96,32)
              const float* __restrict__ bih,               // (2,96)
              const float* __restrict__ bhh,               // (2,96)
              unsigned short* __restrict__ bout)           // f16 bits (B,T,64)
{
    const int tid  = threadIdx.x;
    const int lane = tid & 63;
    const int wv   = tid >> 6;
    const int g    = blockIdx.x * 4 + wv;        // 0..2047
    const int d    = g >> 10;
    const int b0   = (g & 1023) * 16;            // 16 seqs per wave
    const int col  = lane & 15;
    const int qd   = lane >> 4;

    // ---- Whh A-frags (single f16), permuted rows, exp2-prescaled ----
    f16x8 whhF[6];
    {
        const float* wsrc = Whh + d * 96 * 32;
        #pragma unroll
        for (int t = 0; t < 6; ++t) {
            const float sc = (t < 4) ? SR : SN;
            const int row = (t >> 1) * 32 + 8 * (col >> 2) + 4 * (t & 1) + (col & 3);
            const float* pr = wsrc + row * 32 + qd * 8;
            unsigned short wbits[8];
            #pragma unroll
            for (int j = 0; j < 8; ++j) wbits[j] = f2h(pr[j] * sc);
            whhF[t] = __builtin_bit_cast(f16x8, *(uint4*)wbits);
        }
    }

    // ---- Wih A-frags (single f16, permuted, prescaled) or L0 scalar weights ----
    f16x8 wihF[6][2];
    float w0c[6][4], w1c[6][4];
    if constexpr (!IS_L0) {
        const float* wsrc = Wih + d * 96 * 64;
        #pragma unroll
        for (int t = 0; t < 6; ++t) {
            const float sc = (t < 4) ? SR : SN;
            const int row = (t >> 1) * 32 + 8 * (col >> 2) + 4 * (t & 1) + (col & 3);
            #pragma unroll
            for (int kc = 0; kc < 2; ++kc) {
                const float* pr = wsrc + row * 64 + kc * 32 + qd * 8;
                unsigned short wbits[8];
                #pragma unroll
                for (int j = 0; j < 8; ++j) wbits[j] = f2h(pr[j] * sc);
                wihF[t][kc] = __builtin_bit_cast(f16x8, *(uint4*)wbits);
            }
        }
    } else {
        #pragma unroll
        for (int t = 0; t < 6; ++t) {
            const float sc = (t < 4) ? SR : SN;
            #pragma unroll
            for (int q = 0; q < 4; ++q) {
                const int row = (t >> 1) * 32 + 8 * qd + 4 * (t & 1) + q;
                const float* pr = Wih + d * 96 * 2 + row * 2;
                w0c[t][q] = pr[0] * sc;
                w1c[t][q] = pr[1] * sc;
            }
        }
    }

    // ---- biases as C-operand frags (prescaled) ----
    f32x4 biasIn[6], biasHN[2];
    {
        const float* bi = bih + d * 96;
        const float* bh = bhh + d * 96;
        #pragma unroll
        for (int t = 0; t < 4; ++t) {
            const int off = (t >> 1) * 32 + 8 * qd + 4 * (t & 1);
            float4 a = *(const float4*)(bi + off);
            float4 b = *(const float4*)(bh + off);
            biasIn[t][0] = (a.x + b.x) * SR; biasIn[t][1] = (a.y + b.y) * SR;
            biasIn[t][2] = (a.z + b.z) * SR; biasIn[t][3] = (a.w + b.w) * SR;
        }
        #pragma unroll
        for (int T = 0; T < 2; ++T) {
            const int off = 64 + 8 * qd + 4 * T;
            float4 a = *(const float4*)(bi + off);
            float4 b = *(const float4*)(bh + off);
            biasIn[4 + T][0] = a.x * SN; biasIn[4 + T][1] = a.y * SN;
            biasIn[4 + T][2] = a.z * SN; biasIn[4 + T][3] = a.w * SN;
            biasHN[T][0] = b.x * SN; biasHN[T][1] = b.y * SN;
            biasHN[T][2] = b.z * SN; biasHN[T][3] = b.w * SN;
        }
    }

    const int t0 = d ? (TT - 1) : 0;
    const int dt = d ? -1 : 1;

    f16x8 hF = {};
    float hprev[2][4] = {{0.f,0.f,0.f,0.f},{0.f,0.f,0.f,0.f}};

    // ---- recurrence MFMAs (single f16 Whh; 6 MFMAs, chain depth 1) ----
    auto REC = [&](f32x4 (&acc)[6], f32x4 (&accHN)[2]) {
        #pragma unroll
        for (int t = 0; t < 4; ++t)
            acc[t] = mfma16h(whhF[t], hF, acc[t]);
        #pragma unroll
        for (int T = 0; T < 2; ++T)
            accHN[T] = mfma16h(whhF[4 + T], hF, biasHN[T]);
    };

    // ---- next step's input projection (h-independent) ----
    auto PROJ = [&](f32x4 (&accN)[6], uint4 nx0, uint4 nx1, float2 nxs) {
        if constexpr (!IS_L0) {
            f16x8 a0 = __builtin_bit_cast(f16x8, nx0);
            f16x8 a1 = __builtin_bit_cast(f16x8, nx1);
            #pragma unroll
            for (int t = 0; t < 6; ++t) {
                accN[t] = mfma16h(wihF[t][0], a0, biasIn[t]);
                accN[t] = mfma16h(wihF[t][1], a1, accN[t]);
            }
        } else {
            #pragma unroll
            for (int t = 0; t < 6; ++t)
                #pragma unroll
                for (int q = 0; q < 4; ++q)
                    accN[t][q] = fmaf(nxs.x, w0c[t][q], fmaf(nxs.y, w1c[t][q], biasIn[t][q]));
        }
    };

    // ---- gates + pack f16 + store; updates hF ----
    auto GATES = [&](f32x4 (&acc)[6], f32x4 (&accHN)[2], unsigned short* outp) {
        unsigned int hw[4];
        #pragma unroll
        for (int T = 0; T < 2; ++T) {
            float h0 = hprev[T][0], h1 = hprev[T][1];
            float h2 = hprev[T][2], h3 = hprev[T][3];
            gate_pair(acc[T][0], acc[T][1], acc[2 + T][0], acc[2 + T][1],
                      acc[4 + T][0], acc[4 + T][1], accHN[T][0], accHN[T][1], h0, h1);
            gate_pair(acc[T][2], acc[T][3], acc[2 + T][2], acc[2 + T][3],
                      acc[4 + T][2], acc[4 + T][3], accHN[T][2], accHN[T][3], h2, h3);
            hprev[T][0] = h0; hprev[T][1] = h1; hprev[T][2] = h2; hprev[T][3] = h3;
            hw[2 * T]     = cvt_pkh(h0, h1);
            hw[2 * T + 1] = cvt_pkh(h2, h3);
        }
        hF = __builtin_bit_cast(f16x8, *(uint4*)hw);
        *(uint4*)outp = *(uint4*)hw;
    };

    // ---- x streams: even loads x[2k+2], odd loads x[2k+3] ----
    f32x4 accA[6], accB[6], accHN[2];
    uint4 xc0 = {}, xc1 = {}, xe0 = {}, xe1 = {};
    float2 xsc = {}, xse = {};
    const unsigned short* xptrE = nullptr; const unsigned short* xptrO = nullptr;
    const float* xfpE = nullptr; const float* xfpO = nullptr;

    if constexpr (!IS_L0) {
        const unsigned short* p0 = bin + ((size_t)(b0 + col) * TT + t0) * 64 + qd * 8;
        uint4 a = *(const uint4*)p0, b = *(const uint4*)(p0 + 32);
        PROJ(accA, a, b, {});                         // acc for step 0
        const unsigned short* p1 = p0 + dt * 64;
        xc0 = *(const uint4*)p1; xc1 = *(const uint4*)(p1 + 32);   // x[1]
        xptrE = p0 + dt * 128;                        // x[2]
        xptrO = p0 + dt * 192;                        // x[3]
    } else {
        const float* p0 = x0 + ((size_t)(b0 + col) * TT + t0) * 2;
        float2 xs0 = *(const float2*)p0;
        PROJ(accA, {}, {}, xs0);
        xsc = *(const float2*)(p0 + dt * 2);          // x[1]
        xfpE = p0 + dt * 4;                           // x[2]
        xfpO = p0 + dt * 6;                           // x[3]
    }
    unsigned short* optrA = bout + ((size_t)(b0 + col) * TT + t0) * 64 + d * 32 + qd * 8;
    unsigned short* optrB = optrA + dt * 64;

    for (int k = 0; k < 31; ++k) {                    // steps 0..61
        if constexpr (!IS_L0) {
            xe0 = *(const uint4*)xptrE; xe1 = *(const uint4*)(xptrE + 32);
            xptrE += dt * 128;
        } else { xse = *(const float2*)xfpE; xfpE += dt * 4; }
        REC(accA, accHN);
        PROJ(accB, xc0, xc1, xsc);
        GATES(accA, accHN, optrA); optrA += dt * 128;
        if constexpr (!IS_L0) {
            xc0 = *(const uint4*)xptrO; xc1 = *(const uint4*)(xptrO + 32);
            xptrO += dt * 128;
        } else { xsc = *(const float2*)xfpO; xfpO += dt * 4; }
        REC(accB, accHN);
        PROJ(accA, xe0, xe1, xse);
        GATES(accB, accHN, optrB); optrB += dt * 128;
    }
    REC(accA, accHN);                                 // step 62
    PROJ(accB, xc0, xc1, xsc);
    GATES(accA, accHN, optrA);
    REC(accB, accHN);                                 // step 63
    GATES(accB, accHN, optrB);
}

__global__ __launch_bounds__(256)
void fc_kernel(const unsigned short* __restrict__ bin,   // f16 bits (B*T, 64)
               const float* __restrict__ Wfc,
               const float* __restrict__ bfc,
               float* __restrict__ out)
{
    __shared__ float sw[128];
    __shared__ float sb[2];
    const int tid = threadIdx.x;
    if (tid < 128) sw[tid] = Wfc[tid];
    if (tid < 2) sb[tid] = bfc[tid];
    __syncthreads();

    const size_t uidx = (size_t)blockIdx.x * 256 + tid;
    const unsigned short* ip = bin + uidx * 64;
    float a0 = sb[0], a1 = sb[1];
    #pragma unroll
    for (int i = 0; i < 64; i += 8) {
        uint4 raw = *(const uint4*)(ip + i);
        #pragma unroll
        for (int w = 0; w < 4; ++w) {
            unsigned int uu = ((const unsigned int*)&raw)[w];
            float f0 = (float)__builtin_bit_cast(_Float16, (unsigned short)(uu & 0xffffu));
            float f1 = (float)__builtin_bit_cast(_Float16, (unsigned short)(uu >> 16));
            a0 = fmaf(f0, sw[i + 2 * w], a0);
            a1 = fmaf(f0, sw[64 + i + 2 * w], a1);
            a0 = fmaf(f1, sw[i + 2 * w + 1], a0);
            a1 = fmaf(f1, sw[64 + i + 2 * w + 1], a1);
        }
    }
    float2 o;
    o.x = tanh_fast(a0);
    o.y = tanh_fast(a1);
    *(float2*)&out[2 * uidx] = o;
}

extern "C" void kernel_launch(void* const* d_in, const int* in_sizes, int n_in,
                              void* d_out, int out_size, void* d_ws, size_t ws_size,
                              hipStream_t stream)
{
    const float* x    = (const float*)d_in[0];
    const float* Wih0 = (const float*)d_in[1];
    const float* Whh0 = (const float*)d_in[2];
    const float* bih0 = (const float*)d_in[3];
    const float* bhh0 = (const float*)d_in[4];
    const float* WihL = (const float*)d_in[5];
    const float* WhhL = (const float*)d_in[6];
    const float* bihL = (const float*)d_in[7];
    const float* bhhL = (const float*)d_in[8];
    const float* Wfc  = (const float*)d_in[9];
    const float* bfc  = (const float*)d_in[10];

    unsigned short* buf0 = (unsigned short*)d_ws;
    unsigned short* buf1 = buf0 + (size_t)BB * TT * 64;
    float* out = (float*)d_out;

    gru_mfma<true><<<512, 256, 0, stream>>>(
        x, nullptr, Wih0, Whh0, bih0, bhh0, buf0);
    gru_mfma<false><<<512, 256, 0, stream>>>(
        nullptr, buf0, WihL, WhhL, bihL, bhhL, buf1);
    gru_mfma<false><<<512, 256, 0, stream>>>(
        nullptr, buf1, WihL + 2 * 96 * 64, WhhL + 2 * 96 * 32,
        bihL + 2 * 96, bhhL + 2 * 96, buf0);
    fc_kernel<<<(BB * TT) / 256, 256, 0, stream>>>(buf0, Wfc, bfc, out);
}

// Round 13
// 315.680 us; speedup vs baseline: 6.4542x; 1.0581x over previous
//
#include <hip/hip_runtime.h>
#include <cstdint>
#include <cstddef>

// GRU B=16384 T=64 H=32, 3 bidir layers + FC(64->2) + tanh.
// R12: activation buffers transposed to (T, B, 64) f16. At step t each wave
// now reads/writes 16 consecutive b-rows = contiguous 2KB, and all waves
// stream the t-planes in lockstep -> DRAM-friendly sequential sweep
// (R11 was bound at 2.4 TB/s by 64B-granule scatter at 8KB stride).
// Datapath unchanged from R11: full f16 (Whh/Wih/h/activations), fp32 acc,
// 16 seqs/wave, permuted gate rows (D-frag==B-frag), zero LDS, exp2-folded
// weights, shared rcp, pipelined PROJ, 2x unroll.

#define BB 16384
#define TT 64
#define ST ((size_t)BB * 64)   // shorts per t-plane

typedef __attribute__((ext_vector_type(8))) _Float16 f16x8;
typedef __attribute__((ext_vector_type(4))) float f32x4;

#if __has_builtin(__builtin_amdgcn_exp2f)
#define EXP2(x) __builtin_amdgcn_exp2f(x)
#else
#define EXP2(x) exp2f(x)
#endif
#if __has_builtin(__builtin_amdgcn_rcpf)
#define RCP(x) __builtin_amdgcn_rcpf(x)
#else
#define RCP(x) (1.0f / (x))
#endif

#define SR (-1.4426950408889634f)   // -log2(e)   for r,z gates
#define SN (-2.8853900817779268f)   // -2*log2(e) for n gate

__device__ __forceinline__ float tanh_fast(float x) { return 2.0f / (1.0f + __expf(-2.0f * x)) - 1.0f; }
__device__ __forceinline__ unsigned short f2h(float f) {
    _Float16 h = (_Float16)f;                      // RNE
    return __builtin_bit_cast(unsigned short, h);
}
// pack two f32 -> two f16 in one dword (v_cvt_pkrtz_f16_f32)
__device__ __forceinline__ unsigned int cvt_pkh(float a, float b) {
#if __has_builtin(__builtin_amdgcn_cvt_pkrtz)
    typedef __fp16 h2_t __attribute__((ext_vector_type(2)));
    h2_t p = __builtin_amdgcn_cvt_pkrtz(a, b);
    return __builtin_bit_cast(unsigned int, p);
#else
    return (unsigned int)f2h(a) | ((unsigned int)f2h(b) << 16);
#endif
}
__device__ __forceinline__ f32x4 mfma16h(f16x8 a, f16x8 b, f32x4 c) {
    return __builtin_amdgcn_mfma_f32_16x16x32_f16(a, b, c, 0, 0, 0);
}

// Gates for a q-pair. Inputs are exp2-prescaled preactivations (C carried bias).
// sigma(x) = rcp(1+exp2(SR*x)); tanh(v) = 2*rcp(1+exp2(SN*v)) - 1.
__device__ __forceinline__ void gate_pair(float aR0, float aR1, float aZ0, float aZ1,
                                          float xN0, float xN1, float hN0, float hN1,
                                          float& hp0, float& hp1) {
    float er0 = EXP2(aR0), er1 = EXP2(aR1);
    float ez0 = EXP2(aZ0), ez1 = EXP2(aZ1);
    float Ar0 = 1.f + er0, Ar1 = 1.f + er1;
    float Az0 = 1.f + ez0, Az1 = 1.f + ez1;
    float iR = RCP(Ar0 * Ar1);
    float iZ = RCP(Az0 * Az1);
    float r0 = iR * Ar1, r1 = iR * Ar0;
    float z0 = iZ * Az1, z1 = iZ * Az0;
    float v0 = fmaf(r0, hN0, xN0), v1 = fmaf(r1, hN1, xN1);
    float en0 = EXP2(v0), en1 = EXP2(v1);
    float An0 = 1.f + en0, An1 = 1.f + en1;
    float iN = RCP(An0 * An1);
    float n0 = fmaf(2.f, iN * An1, -1.f);
    float n1 = fmaf(2.f, iN * An0, -1.f);
    hp0 = fmaf(z0, hp0 - n0, n0);
    hp1 = fmaf(z1, hp1 - n1, n1);
}

// A: lane = A[m=lane&15][k=(lane>>4)*8+j]   B: lane = B[k=(lane>>4)*8+j][n=lane&15]
// D: lane = D[row=(lane>>4)*4+reg][col=lane&15]
// Gate-row permutation: block row position (T*16 + qd*4 + q) <- original unit 8qd+4T+q.

template<bool IS_L0>
__global__ __launch_bounds__(256, 2)
void gru_mfma(const float* __restrict__ x0,
              const unsigned short* __restrict__ bin,      // f16 bits (T,B,64)
              const float* __restrict__ Wih,               // (2,96,I)
              const float* __restrict__ Whh,               // (2,96,32)
              const float* __restrict__ bih,               // (2,96)
              const float* __restrict__ bhh,               // (2,96)
              unsigned short* __restrict__ bout)           // f16 bits (T,B,64)
{
    const int tid  = threadIdx.x;
    const int lane = tid & 63;
    const int wv   = tid >> 6;
    const int g    = blockIdx.x * 4 + wv;        // 0..2047
    const int d    = g >> 10;
    const int b0   = (g & 1023) * 16;            // 16 seqs per wave
    const int col  = lane & 15;
    const int qd   = lane >> 4;

    // ---- Whh A-frags (single f16), permuted rows, exp2-prescaled ----
    f16x8 whhF[6];
    {
        const float* wsrc = Whh + d * 96 * 32;
        #pragma unroll
        for (int t = 0; t < 6; ++t) {
            const float sc = (t < 4) ? SR : SN;
            const int row = (t >> 1) * 32 + 8 * (col >> 2) + 4 * (t & 1) + (col & 3);
            const float* pr = wsrc + row * 32 + qd * 8;
            unsigned short wbits[8];
            #pragma unroll
            for (int j = 0; j < 8; ++j) wbits[j] = f2h(pr[j] * sc);
            whhF[t] = __builtin_bit_cast(f16x8, *(uint4*)wbits);
        }
    }

    // ---- Wih A-frags (single f16, permuted, prescaled) or L0 scalar weights ----
    f16x8 wihF[6][2];
    float w0c[6][4], w1c[6][4];
    if constexpr (!IS_L0) {
        const float* wsrc = Wih + d * 96 * 64;
        #pragma unroll
        for (int t = 0; t < 6; ++t) {
            const float sc = (t < 4) ? SR : SN;
            const int row = (t >> 1) * 32 + 8 * (col >> 2) + 4 * (t & 1) + (col & 3);
            #pragma unroll
            for (int kc = 0; kc < 2; ++kc) {
                const float* pr = wsrc + row * 64 + kc * 32 + qd * 8;
                unsigned short wbits[8];
                #pragma unroll
                for (int j = 0; j < 8; ++j) wbits[j] = f2h(pr[j] * sc);
                wihF[t][kc] = __builtin_bit_cast(f16x8, *(uint4*)wbits);
            }
        }
    } else {
        #pragma unroll
        for (int t = 0; t < 6; ++t) {
            const float sc = (t < 4) ? SR : SN;
            #pragma unroll
            for (int q = 0; q < 4; ++q) {
                const int row = (t >> 1) * 32 + 8 * qd + 4 * (t & 1) + q;
                const float* pr = Wih + d * 96 * 2 + row * 2;
                w0c[t][q] = pr[0] * sc;
                w1c[t][q] = pr[1] * sc;
            }
        }
    }

    // ---- biases as C-operand frags (prescaled) ----
    f32x4 biasIn[6], biasHN[2];
    {
        const float* bi = bih + d * 96;
        const float* bh = bhh + d * 96;
        #pragma unroll
        for (int t = 0; t < 4; ++t) {
            const int off = (t >> 1) * 32 + 8 * qd + 4 * (t & 1);
            float4 a = *(const float4*)(bi + off);
            float4 b = *(const float4*)(bh + off);
            biasIn[t][0] = (a.x + b.x) * SR; biasIn[t][1] = (a.y + b.y) * SR;
            biasIn[t][2] = (a.z + b.z) * SR; biasIn[t][3] = (a.w + b.w) * SR;
        }
        #pragma unroll
        for (int T = 0; T < 2; ++T) {
            const int off = 64 + 8 * qd + 4 * T;
            float4 a = *(const float4*)(bi + off);
            float4 b = *(const float4*)(bh + off);
            biasIn[4 + T][0] = a.x * SN; biasIn[4 + T][1] = a.y * SN;
            biasIn[4 + T][2] = a.z * SN; biasIn[4 + T][3] = a.w * SN;
            biasHN[T][0] = b.x * SN; biasHN[T][1] = b.y * SN;
            biasHN[T][2] = b.z * SN; biasHN[T][3] = b.w * SN;
        }
    }

    const int t0 = d ? (TT - 1) : 0;
    const int dt = d ? -1 : 1;
    const ptrdiff_t dplane = (ptrdiff_t)dt * (ptrdiff_t)ST;   // one t-plane step

    f16x8 hF = {};
    float hprev[2][4] = {{0.f,0.f,0.f,0.f},{0.f,0.f,0.f,0.f}};

    // ---- recurrence MFMAs (single f16 Whh; 6 MFMAs, chain depth 1) ----
    auto REC = [&](f32x4 (&acc)[6], f32x4 (&accHN)[2]) {
        #pragma unroll
        for (int t = 0; t < 4; ++t)
            acc[t] = mfma16h(whhF[t], hF, acc[t]);
        #pragma unroll
        for (int T = 0; T < 2; ++T)
            accHN[T] = mfma16h(whhF[4 + T], hF, biasHN[T]);
    };

    // ---- next step's input projection (h-independent) ----
    auto PROJ = [&](f32x4 (&accN)[6], uint4 nx0, uint4 nx1, float2 nxs) {
        if constexpr (!IS_L0) {
            f16x8 a0 = __builtin_bit_cast(f16x8, nx0);
            f16x8 a1 = __builtin_bit_cast(f16x8, nx1);
            #pragma unroll
            for (int t = 0; t < 6; ++t) {
                accN[t] = mfma16h(wihF[t][0], a0, biasIn[t]);
                accN[t] = mfma16h(wihF[t][1], a1, accN[t]);
            }
        } else {
            #pragma unroll
            for (int t = 0; t < 6; ++t)
                #pragma unroll
                for (int q = 0; q < 4; ++q)
                    accN[t][q] = fmaf(nxs.x, w0c[t][q], fmaf(nxs.y, w1c[t][q], biasIn[t][q]));
        }
    };

    // ---- gates + pack f16 + store; updates hF ----
    auto GATES = [&](f32x4 (&acc)[6], f32x4 (&accHN)[2], unsigned short* outp) {
        unsigned int hw[4];
        #pragma unroll
        for (int T = 0; T < 2; ++T) {
            float h0 = hprev[T][0], h1 = hprev[T][1];
            float h2 = hprev[T][2], h3 = hprev[T][3];
            gate_pair(acc[T][0], acc[T][1], acc[2 + T][0], acc[2 + T][1],
                      acc[4 + T][0], acc[4 + T][1], accHN[T][0], accHN[T][1], h0, h1);
            gate_pair(acc[T][2], acc[T][3], acc[2 + T][2], acc[2 + T][3],
                      acc[4 + T][2], acc[4 + T][3], accHN[T][2], accHN[T][3], h2, h3);
            hprev[T][0] = h0; hprev[T][1] = h1; hprev[T][2] = h2; hprev[T][3] = h3;
            hw[2 * T]     = cvt_pkh(h0, h1);
            hw[2 * T + 1] = cvt_pkh(h2, h3);
        }
        hF = __builtin_bit_cast(f16x8, *(uint4*)hw);
        *(uint4*)outp = *(uint4*)hw;
    };

    // ---- x streams: even loads x[2k+2], odd loads x[2k+3] ----
    f32x4 accA[6], accB[6], accHN[2];
    uint4 xc0 = {}, xc1 = {}, xe0 = {}, xe1 = {};
    float2 xsc = {}, xse = {};
    const unsigned short* xptrE = nullptr; const unsigned short* xptrO = nullptr;
    const float* xfpE = nullptr; const float* xfpO = nullptr;

    if constexpr (!IS_L0) {
        const unsigned short* p0 = bin + (size_t)t0 * ST + (size_t)(b0 + col) * 64 + qd * 8;
        uint4 a = *(const uint4*)p0, b = *(const uint4*)(p0 + 32);
        PROJ(accA, a, b, {});                         // acc for step 0
        const unsigned short* p1 = p0 + dplane;
        xc0 = *(const uint4*)p1; xc1 = *(const uint4*)(p1 + 32);   // x[1]
        xptrE = p0 + 2 * dplane;                      // x[2]
        xptrO = p0 + 3 * dplane;                      // x[3]
    } else {
        const float* p0 = x0 + ((size_t)(b0 + col) * TT + t0) * 2;
        float2 xs0 = *(const float2*)p0;
        PROJ(accA, {}, {}, xs0);
        xsc = *(const float2*)(p0 + dt * 2);          // x[1]
        xfpE = p0 + dt * 4;                           // x[2]
        xfpO = p0 + dt * 6;                           // x[3]
    }
    unsigned short* optrA = bout + (size_t)t0 * ST + (size_t)(b0 + col) * 64 + d * 32 + qd * 8;
    unsigned short* optrB = optrA + dplane;

    for (int k = 0; k < 31; ++k) {                    // steps 0..61
        if constexpr (!IS_L0) {
            xe0 = *(const uint4*)xptrE; xe1 = *(const uint4*)(xptrE + 32);
            xptrE += 2 * dplane;
        } else { xse = *(const float2*)xfpE; xfpE += dt * 4; }
        REC(accA, accHN);
        PROJ(accB, xc0, xc1, xsc);
        GATES(accA, accHN, optrA); optrA += 2 * dplane;
        if constexpr (!IS_L0) {
            xc0 = *(const uint4*)xptrO; xc1 = *(const uint4*)(xptrO + 32);
            xptrO += 2 * dplane;
        } else { xsc = *(const float2*)xfpO; xfpO += dt * 4; }
        REC(accB, accHN);
        PROJ(accA, xe0, xe1, xse);
        GATES(accB, accHN, optrB); optrB += 2 * dplane;
    }
    REC(accA, accHN);                                 // step 62
    PROJ(accB, xc0, xc1, xsc);
    GATES(accA, accHN, optrA);
    REC(accB, accHN);                                 // step 63
    GATES(accB, accHN, optrB);
}

__global__ __launch_bounds__(256)
void fc_kernel(const unsigned short* __restrict__ bin,   // f16 bits (T,B,64)
               const float* __restrict__ Wfc,
               const float* __restrict__ bfc,
               float* __restrict__ out)                  // (B,T,2) fp32
{
    __shared__ float sw[128];
    __shared__ float sb[2];
    const int tid = threadIdx.x;
    if (tid < 128) sw[tid] = Wfc[tid];
    if (tid < 2) sb[tid] = bfc[tid];
    __syncthreads();

    const size_t uidx = (size_t)blockIdx.x * 256 + tid;   // row in (t,b) order
    const size_t t = uidx >> 14;                          // uidx / BB
    const size_t b = uidx & (BB - 1);
    const unsigned short* ip = bin + uidx * 64;           // coalesced read
    float a0 = sb[0], a1 = sb[1];
    #pragma unroll
    for (int i = 0; i < 64; i += 8) {
        uint4 raw = *(const uint4*)(ip + i);
        #pragma unroll
        for (int w = 0; w < 4; ++w) {
            unsigned int uu = ((const unsigned int*)&raw)[w];
            float f0 = (float)__builtin_bit_cast(_Float16, (unsigned short)(uu & 0xffffu));
            float f1 = (float)__builtin_bit_cast(_Float16, (unsigned short)(uu >> 16));
            a0 = fmaf(f0, sw[i + 2 * w], a0);
            a1 = fmaf(f0, sw[64 + i + 2 * w], a1);
            a0 = fmaf(f1, sw[i + 2 * w + 1], a0);
            a1 = fmaf(f1, sw[64 + i + 2 * w + 1], a1);
        }
    }
    float2 o;
    o.x = tanh_fast(a0);
    o.y = tanh_fast(a1);
    *(float2*)&out[(b * TT + t) * 2] = o;
}

extern "C" void kernel_launch(void* const* d_in, const int* in_sizes, int n_in,
                              void* d_out, int out_size, void* d_ws, size_t ws_size,
                              hipStream_t stream)
{
    const float* x    = (const float*)d_in[0];
    const float* Wih0 = (const float*)d_in[1];
    const float* Whh0 = (const float*)d_in[2];
    const float* bih0 = (const float*)d_in[3];
    const float* bhh0 = (const float*)d_in[4];
    const float* WihL = (const float*)d_in[5];
    const float* WhhL = (const float*)d_in[6];
    const float* bihL = (const float*)d_in[7];
    const float* bhhL = (const float*)d_in[8];
    const float* Wfc  = (const float*)d_in[9];
    const float* bfc  = (const float*)d_in[10];

    unsigned short* buf0 = (unsigned short*)d_ws;           // (T,B,64) f16
    unsigned short* buf1 = buf0 + (size_t)TT * BB * 64;     // (T,B,64) f16
    float* out = (float*)d_out;

    gru_mfma<true><<<512, 256, 0, stream>>>(
        x, nullptr, Wih0, Whh0, bih0, bhh0, buf0);
    gru_mfma<false><<<512, 256, 0, stream>>>(
        nullptr, buf0, WihL, WhhL, bihL, bhhL, buf1);
    gru_mfma<false><<<512, 256, 0, stream>>>(
        nullptr, buf1, WihL + 2 * 96 * 64, WhhL + 2 * 96 * 32,
        bihL + 2 * 96, bhhL + 2 * 96, buf0);
    fc_kernel<<<(BB * TT) / 256, 256, 0, stream>>>(buf0, Wfc, bfc, out);
}